// Round 4
// baseline (293.741 us; speedup 1.0000x reference)
//
#include <hip/hip_runtime.h>

#define RAYS 65536
#define NS   192

__device__ __forceinline__ int   f2i(float x){ return __builtin_bit_cast(int, x); }
__device__ __forceinline__ float i2f(int x)  { return __builtin_bit_cast(float, x); }

// pin a float to a VGPR at this program point: the load feeding it must have
// completed here, and the value stays live. Defeats load sinking (rule #17).
#define PIN(x) asm volatile("" : "+v"(x))

// v_mov_b32_dpp with old=0, bound_ctrl:0 (invalid lanes -> 0)
template<int CTRL, int ROWMASK>
__device__ __forceinline__ float dpp0(float x){
    return i2f(__builtin_amdgcn_update_dpp(0, f2i(x), CTRL, ROWMASK, 0xF, true));
}
template<int OFF>
__device__ __forceinline__ float swz(float x){
    return i2f(__builtin_amdgcn_ds_swizzle(f2i(x), OFF));
}

// partner value at sub-lane XOR distance JL (within each 32-lane half)
template<int JL>
__device__ __forceinline__ float partner(float x){
    if      constexpr (JL == 1)  return dpp0<0xB1, 0xF>(x);   // quad_perm xor1
    else if constexpr (JL == 2)  return dpp0<0x4E, 0xF>(x);   // quad_perm xor2
    else if constexpr (JL == 3)  return dpp0<0x1B, 0xF>(x);   // quad_perm [3,2,1,0] = xor3
    else if constexpr (JL == 4)  return swz<0x101F>(x);       // xor4
    else if constexpr (JL == 7)  return swz<0x1C1F>(x);       // xor7
    else if constexpr (JL == 8)  return swz<0x201F>(x);       // xor8
    else if constexpr (JL == 15) return swz<0x3C1F>(x);       // xor15
    else if constexpr (JL == 16) return swz<0x401F>(x);       // xor16
    else                         return swz<0x7C1F>(x);       // xor31
}

// ascending in-lane compare-exchange: 2 VALU (fmin+fmax)
__device__ __forceinline__ void ce(float &a, float &b){
    float mn = fminf(a, b), mx = fmaxf(a, b);
    a = mn; b = mx;
}

// normalized cross-lane halver phase at lane distance JL; 'lower' = ((sl&JL)==0).
template<int JL>
__device__ __forceinline__ void xphase(float v[8], bool lower){
    #pragma unroll
    for (int r = 0; r < 8; ++r){
        float p = partner<JL>(v[r]);
        v[r] = ((v[r] < p) == lower) ? v[r] : p;
    }
}

// mirror phase opening a merge of two ascending runs: (sl, r) pairs with (sl^JL, 7-r).
template<int JL>
__device__ __forceinline__ void xmirror(float v[8], bool lower){
    #pragma unroll
    for (int r = 0; r < 4; ++r){
        float pa = partner<JL>(v[7 - r]);
        float pb = partner<JL>(v[r]);
        v[r]     = ((v[r]     < pa) == lower) ? v[r]     : pa;
        v[7 - r] = ((v[7 - r] < pb) == lower) ? v[7 - r] : pb;
    }
}

// in-lane bitonic cleanup (strides 4,2,1), ascending
__device__ __forceinline__ void rmerge(float v[8]){
    ce(v[0],v[4]); ce(v[1],v[5]); ce(v[2],v[6]); ce(v[3],v[7]);
    ce(v[0],v[2]); ce(v[1],v[3]); ce(v[4],v[6]); ce(v[5],v[7]);
    ce(v[0],v[1]); ce(v[2],v[3]); ce(v[4],v[5]); ce(v[6],v[7]);
}

// Batcher odd-even 8-sorter, 19 CEs, ascending
__device__ __forceinline__ void sort8(float v[8]){
    ce(v[0],v[1]); ce(v[2],v[3]); ce(v[4],v[5]); ce(v[6],v[7]);
    ce(v[0],v[2]); ce(v[1],v[3]); ce(v[4],v[6]); ce(v[5],v[7]);
    ce(v[1],v[2]); ce(v[5],v[6]);
    ce(v[0],v[4]); ce(v[1],v[5]); ce(v[2],v[6]); ce(v[3],v[7]);
    ce(v[2],v[4]); ce(v[3],v[5]);
    ce(v[1],v[2]); ce(v[3],v[4]); ce(v[5],v[6]);
}

// 32-lane butterfly sum (both halves independently)
__device__ __forceinline__ float halfsum(float a){
    a += dpp0<0xB1, 0xF>(a);
    a += dpp0<0x4E, 0xF>(a);
    a += swz<0x101F>(a);
    a += swz<0x201F>(a);
    a += swz<0x401F>(a);
    return a;
}

__global__ __launch_bounds__(256) void nerf_integrate(
    const float* __restrict__ t,
    const float* __restrict__ sigma,
    const float* __restrict__ c,
    float* __restrict__ out)
{
    const int tid  = threadIdx.x;
    const int lane = tid & 63;
    const int sl   = tid & 31;                     // sub-lane within the ray's 32 lanes
    const int ray  = blockIdx.x * 8 + (tid >> 5);  // 2 rays per wave, 8 per block

    const bool lo1  = (sl & 1)  == 0;
    const bool lo2  = (sl & 2)  == 0;
    const bool lo4  = (sl & 4)  == 0;
    const bool lo8  = (sl & 8)  == 0;
    const bool lo16 = (sl & 16) == 0;

    const bool act = (sl < 24);                    // lane's 8 elements all < 192
    const int  sls = act ? sl : 0;                 // clamped: inactive lanes load row
                                                   // start (finite garbage, never used)

    // ======== ISSUE ALL LOADS, THEN PIN — one batched latency, not three ======
    const float* trow = t + (size_t)ray * 193;
    float v[8];
    #pragma unroll
    for (int j = 0; j < 6; ++j) v[j] = trow[32 * j + sl];   // coalesced
    float t192 = trow[192];                                  // 1 line per half

    const float* srow = sigma + (size_t)ray * NS + 8 * sls;
    float4 s0 = *reinterpret_cast<const float4*>(srow);
    float4 s1 = *reinterpret_cast<const float4*>(srow + 4);

    const float* crow = c + (size_t)ray * (NS * 3) + 24 * sls;
    float4 c0 = *reinterpret_cast<const float4*>(crow);
    float4 c1 = *reinterpret_cast<const float4*>(crow + 4);
    float4 c2 = *reinterpret_cast<const float4*>(crow + 8);
    float4 c3 = *reinterpret_cast<const float4*>(crow + 12);
    float4 c4 = *reinterpret_cast<const float4*>(crow + 16);
    float4 c5 = *reinterpret_cast<const float4*>(crow + 20);

    // pin everything: loads are all in flight together; values stay in VGPRs.
    #pragma unroll
    for (int j = 0; j < 6; ++j) PIN(v[j]);
    PIN(t192);
    PIN(s0.x); PIN(s0.y); PIN(s0.z); PIN(s0.w);
    PIN(s1.x); PIN(s1.y); PIN(s1.z); PIN(s1.w);
    PIN(c0.x); PIN(c0.y); PIN(c0.z); PIN(c0.w);
    PIN(c1.x); PIN(c1.y); PIN(c1.z); PIN(c1.w);
    PIN(c2.x); PIN(c2.y); PIN(c2.z); PIN(c2.w);
    PIN(c3.x); PIN(c3.y); PIN(c3.z); PIN(c3.w);
    PIN(c4.x); PIN(c4.y); PIN(c4.z); PIN(c4.w);
    PIN(c5.x); PIN(c5.y); PIN(c5.z); PIN(c5.w);
    __builtin_amdgcn_sched_barrier(0);

    v[6] = (sl == 0) ? t192 : 1e30f;
    v[7] = 1e30f;

    // ==== mirror-normalized bitonic sort of 256: bits [2:0]=r, [7:3]=sl ====
    sort8(v);
    // merge to 16
    xmirror<1>(v, lo1);
    rmerge(v);
    // merge to 32
    xmirror<3>(v, lo2);
    xphase<1>(v, lo1);
    rmerge(v);
    // merge to 64
    xmirror<7>(v, lo4);
    xphase<2>(v, lo2);
    xphase<1>(v, lo1);
    rmerge(v);
    // merge to 128
    xmirror<15>(v, lo8);
    xphase<4>(v, lo4);
    xphase<2>(v, lo2);
    xphase<1>(v, lo1);
    rmerge(v);
    // merge to 256
    xmirror<31>(v, lo16);
    xphase<8>(v, lo8);
    xphase<4>(v, lo4);
    xphase<2>(v, lo2);
    xphase<1>(v, lo1);
    rmerge(v);

    // ---- neighbor for r=7 (cross-lane, uniform control flow) ----
    float nxt = __shfl(v[0], lane + 1, 64);  // lane31/63 are pads -> don't care

    // ---- sdt (act-select zeroes inactive lanes; garbage sg never escapes) ----
    float sg[8] = { s0.x, s0.y, s0.z, s0.w, s1.x, s1.y, s1.z, s1.w };
    float sdt[8];
    #pragma unroll
    for (int r = 0; r < 8; ++r){
        float tn = (r < 7) ? v[r + 1] : nxt;
        sdt[r] = act ? sg[r] * (tn - v[r]) : 0.0f;
    }

    // ---- prefix sum: in-lane inclusive over 8, then per-half DPP scan ----
    float pre[8];
    float run = 0.0f;
    #pragma unroll
    for (int r = 0; r < 8; ++r){ run += sdt[r]; pre[r] = run; }
    float x = run;
    x += dpp0<0x111, 0xF>(x);   // row_shr:1
    x += dpp0<0x112, 0xF>(x);   // row_shr:2
    x += dpp0<0x114, 0xF>(x);   // row_shr:4
    x += dpp0<0x118, 0xF>(x);   // row_shr:8
    x += dpp0<0x142, 0xA>(x);   // row_bcast:15 into rows 1,3 (per-half scan)
    float laneExcl = x - run;

    // ---- wi via telescoped exponentials: excl_r == incl_{r-1} -> 9 exps ----
    float wi[8];
    float prev = __expf(-laneExcl);
    #pragma unroll
    for (int r = 0; r < 8; ++r){
        float e = __expf(-(laneExcl + pre[r]));
        wi[r] = prev - e;
        prev = e;
    }
    if (act){
        float* wrow = out + (size_t)RAYS * 3 + (size_t)ray * NS + 8 * sl;
        *reinterpret_cast<float4*>(wrow)     = make_float4(wi[0], wi[1], wi[2], wi[3]);
        *reinterpret_cast<float4*>(wrow + 4) = make_float4(wi[4], wi[5], wi[6], wi[7]);
    }

    // ---- rgb from pinned c, per-half reduce (wi==0 kills garbage lanes) ----
    float cf[24] = { c0.x,c0.y,c0.z,c0.w, c1.x,c1.y,c1.z,c1.w,
                     c2.x,c2.y,c2.z,c2.w, c3.x,c3.y,c3.z,c3.w,
                     c4.x,c4.y,c4.z,c4.w, c5.x,c5.y,c5.z,c5.w };
    float a0 = 0.f, a1 = 0.f, a2 = 0.f;
    #pragma unroll
    for (int r = 0; r < 8; ++r){
        a0 += wi[r] * cf[3*r + 0];
        a1 += wi[r] * cf[3*r + 1];
        a2 += wi[r] * cf[3*r + 2];
    }
    a0 = halfsum(a0);
    a1 = halfsum(a1);
    a2 = halfsum(a2);
    if (sl < 3){
        float val = (sl == 0) ? a0 : ((sl == 1) ? a1 : a2);
        out[(size_t)ray * 3 + sl] = val;
    }
}

extern "C" void kernel_launch(void* const* d_in, const int* in_sizes, int n_in,
                              void* d_out, int out_size, void* d_ws, size_t ws_size,
                              hipStream_t stream) {
    const float* t     = (const float*)d_in[0];
    const float* sigma = (const float*)d_in[1];
    const float* c     = (const float*)d_in[2];
    float* out = (float*)d_out;
    nerf_integrate<<<RAYS / 8, 256, 0, stream>>>(t, sigma, c, out);
}

// Round 5
// 292.908 us; speedup vs baseline: 1.0028x; 1.0028x over previous
//
#include <hip/hip_runtime.h>

#define RAYS 65536
#define NS   192

__device__ __forceinline__ int   f2i(float x){ return __builtin_bit_cast(int, x); }
__device__ __forceinline__ float i2f(int x)  { return __builtin_bit_cast(float, x); }

// v_mov_b32_dpp with old=0, bound_ctrl:0 (invalid lanes -> 0)
template<int CTRL, int ROWMASK>
__device__ __forceinline__ float dpp0(float x){
    return i2f(__builtin_amdgcn_update_dpp(0, f2i(x), CTRL, ROWMASK, 0xF, true));
}
template<int OFF>
__device__ __forceinline__ float swz(float x){
    return i2f(__builtin_amdgcn_ds_swizzle(f2i(x), OFF));
}

// partner value at sub-lane XOR distance JL (within each 32-lane half)
template<int JL>
__device__ __forceinline__ float partner(float x){
    if      constexpr (JL == 1)  return dpp0<0xB1, 0xF>(x);   // quad_perm xor1
    else if constexpr (JL == 2)  return dpp0<0x4E, 0xF>(x);   // quad_perm xor2
    else if constexpr (JL == 3)  return dpp0<0x1B, 0xF>(x);   // quad_perm [3,2,1,0] = xor3
    else if constexpr (JL == 4)  return swz<0x101F>(x);       // xor4
    else if constexpr (JL == 7)  return swz<0x1C1F>(x);       // xor7
    else if constexpr (JL == 8)  return swz<0x201F>(x);       // xor8
    else if constexpr (JL == 15) return swz<0x3C1F>(x);       // xor15
    else if constexpr (JL == 16) return swz<0x401F>(x);       // xor16
    else                         return swz<0x7C1F>(x);       // xor31
}

// ascending in-lane compare-exchange: 2 VALU (fmin+fmax)
__device__ __forceinline__ void ce(float &a, float &b){
    float mn = fminf(a, b), mx = fmaxf(a, b);
    a = mn; b = mx;
}

// normalized cross-lane halver phase at lane distance JL; 'lower' = ((sl&JL)==0).
template<int JL>
__device__ __forceinline__ void xphase(float v[8], bool lower){
    #pragma unroll
    for (int r = 0; r < 8; ++r){
        float p = partner<JL>(v[r]);
        v[r] = ((v[r] < p) == lower) ? v[r] : p;
    }
}

// mirror phase opening a merge of two ascending runs: (sl, r) pairs with (sl^JL, 7-r).
template<int JL>
__device__ __forceinline__ void xmirror(float v[8], bool lower){
    #pragma unroll
    for (int r = 0; r < 4; ++r){
        float pa = partner<JL>(v[7 - r]);
        float pb = partner<JL>(v[r]);
        v[r]     = ((v[r]     < pa) == lower) ? v[r]     : pa;
        v[7 - r] = ((v[7 - r] < pb) == lower) ? v[7 - r] : pb;
    }
}

// in-lane bitonic cleanup (strides 4,2,1), ascending
__device__ __forceinline__ void rmerge(float v[8]){
    ce(v[0],v[4]); ce(v[1],v[5]); ce(v[2],v[6]); ce(v[3],v[7]);
    ce(v[0],v[2]); ce(v[1],v[3]); ce(v[4],v[6]); ce(v[5],v[7]);
    ce(v[0],v[1]); ce(v[2],v[3]); ce(v[4],v[5]); ce(v[6],v[7]);
}

// Batcher odd-even 8-sorter, 19 CEs, ascending
__device__ __forceinline__ void sort8(float v[8]){
    ce(v[0],v[1]); ce(v[2],v[3]); ce(v[4],v[5]); ce(v[6],v[7]);
    ce(v[0],v[2]); ce(v[1],v[3]); ce(v[4],v[6]); ce(v[5],v[7]);
    ce(v[1],v[2]); ce(v[5],v[6]);
    ce(v[0],v[4]); ce(v[1],v[5]); ce(v[2],v[6]); ce(v[3],v[7]);
    ce(v[2],v[4]); ce(v[3],v[5]);
    ce(v[1],v[2]); ce(v[3],v[4]); ce(v[5],v[6]);
}

// 32-lane butterfly sum (both halves independently)
__device__ __forceinline__ float halfsum(float a){
    a += dpp0<0xB1, 0xF>(a);
    a += dpp0<0x4E, 0xF>(a);
    a += swz<0x101F>(a);
    a += swz<0x201F>(a);
    a += swz<0x401F>(a);
    return a;
}

// LDS float4 slots: t = 386 (6176B), sigma = 384 (6144B), c = 1152 (18432B)
#define T_F4   386
#define S_F4   384
#define C_F4   1152
#define SM_F4  (T_F4 + S_F4 + C_F4)   // 1922 slots = 30752 B

__global__ __launch_bounds__(256) void nerf_integrate(
    const float* __restrict__ t,
    const float* __restrict__ sigma,
    const float* __restrict__ c,
    float* __restrict__ out)
{
    __shared__ float4 sm4[SM_F4];
    float* smf = reinterpret_cast<float*>(sm4);

    const int tid  = threadIdx.x;
    const int lane = tid & 63;
    const int sl   = tid & 31;      // sub-lane within the ray's 32 lanes
    const int rl   = tid >> 5;      // ray-local index 0..7
    const int ray  = blockIdx.x * 8 + rl;

    // ======== STAGE ALL INPUTS TO LDS ========
    // Loads feed ds_writes that are ordered by the barrier: the compiler CANNOT
    // sink them. All ~9 loads/thread issue together -> one batched latency.
    const float4* tg = reinterpret_cast<const float4*>(t     + (size_t)blockIdx.x * (8 * 193));
    const float4* sg = reinterpret_cast<const float4*>(sigma + (size_t)blockIdx.x * (8 * NS));
    const float4* cg = reinterpret_cast<const float4*>(c     + (size_t)blockIdx.x * (8 * NS * 3));

    float4 r0 = tg[tid];                                   // t[0..255]
    float4 r1 = make_float4(0.f,0.f,0.f,0.f);
    if (tid < T_F4 - 256) r1 = tg[256 + tid];              // t[256..385]
    float4 r2 = sg[tid];                                   // sigma[0..255]
    float4 r3 = make_float4(0.f,0.f,0.f,0.f);
    if (tid < S_F4 - 256) r3 = sg[256 + tid];              // sigma[256..383]
    float4 r4 = cg[tid];
    float4 r5 = cg[256 + tid];
    float4 r6 = cg[512 + tid];
    float4 r7 = cg[768 + tid];
    float4 r8 = make_float4(0.f,0.f,0.f,0.f);
    if (tid < C_F4 - 1024) r8 = cg[1024 + tid];

    sm4[tid] = r0;
    if (tid < T_F4 - 256) sm4[256 + tid] = r1;
    sm4[T_F4 + tid] = r2;
    if (tid < S_F4 - 256) sm4[T_F4 + 256 + tid] = r3;
    sm4[T_F4 + S_F4 + tid]       = r4;
    sm4[T_F4 + S_F4 + 256 + tid] = r5;
    sm4[T_F4 + S_F4 + 512 + tid] = r6;
    sm4[T_F4 + S_F4 + 768 + tid] = r7;
    if (tid < C_F4 - 1024) sm4[T_F4 + S_F4 + 1024 + tid] = r8;
    __syncthreads();

    const bool lo1  = (sl & 1)  == 0;
    const bool lo2  = (sl & 2)  == 0;
    const bool lo4  = (sl & 4)  == 0;
    const bool lo8  = (sl & 8)  == 0;
    const bool lo16 = (sl & 16) == 0;

    // ---- t from LDS (coalesced banks: stride-1 per half-wave) ----
    const float* tl = smf + rl * 193;
    float v[8];
    #pragma unroll
    for (int j = 0; j < 6; ++j) v[j] = tl[32 * j + sl];
    float t192 = tl[192];                 // broadcast
    v[6] = (sl == 0) ? t192 : 1e30f;
    v[7] = 1e30f;

    // ==== mirror-normalized bitonic sort of 256: bits [2:0]=r, [7:3]=sl ====
    sort8(v);
    xmirror<1>(v, lo1);
    rmerge(v);
    xmirror<3>(v, lo2);
    xphase<1>(v, lo1);
    rmerge(v);
    xmirror<7>(v, lo4);
    xphase<2>(v, lo2);
    xphase<1>(v, lo1);
    rmerge(v);
    xmirror<15>(v, lo8);
    xphase<4>(v, lo4);
    xphase<2>(v, lo2);
    xphase<1>(v, lo1);
    rmerge(v);
    xmirror<31>(v, lo16);
    xphase<8>(v, lo8);
    xphase<4>(v, lo4);
    xphase<2>(v, lo2);
    xphase<1>(v, lo1);
    rmerge(v);

    // ---- neighbor for r=7 (cross-lane, uniform control flow) ----
    float nxt = __shfl(v[0], lane + 1, 64);  // lane31/63 are pads -> don't care
    const bool act = (sl < 24);
    const int  sls = act ? sl : 0;           // clamp inactive lanes into the row

    // ---- sigma from LDS ----
    const float* srow = smf + (T_F4 * 4) + rl * NS + 8 * sls;
    float4 s0 = *reinterpret_cast<const float4*>(srow);
    float4 s1 = *reinterpret_cast<const float4*>(srow + 4);
    float sg8[8] = { s0.x, s0.y, s0.z, s0.w, s1.x, s1.y, s1.z, s1.w };

    float sdt[8];
    #pragma unroll
    for (int r = 0; r < 8; ++r){
        float tn = (r < 7) ? v[r + 1] : nxt;
        sdt[r] = act ? sg8[r] * (tn - v[r]) : 0.0f;
    }

    // ---- prefix sum: in-lane inclusive over 8, then per-half DPP scan ----
    float pre[8];
    float run = 0.0f;
    #pragma unroll
    for (int r = 0; r < 8; ++r){ run += sdt[r]; pre[r] = run; }
    float x = run;
    x += dpp0<0x111, 0xF>(x);   // row_shr:1
    x += dpp0<0x112, 0xF>(x);   // row_shr:2
    x += dpp0<0x114, 0xF>(x);   // row_shr:4
    x += dpp0<0x118, 0xF>(x);   // row_shr:8
    x += dpp0<0x142, 0xA>(x);   // row_bcast:15 into rows 1,3 (per-half scan)
    float laneExcl = x - run;

    // ---- wi via telescoped exponentials: excl_r == incl_{r-1} -> 9 exps ----
    float wi[8];
    float prev = __expf(-laneExcl);
    #pragma unroll
    for (int r = 0; r < 8; ++r){
        float e = __expf(-(laneExcl + pre[r]));
        wi[r] = prev - e;
        prev = e;
    }
    if (act){
        float* wrow = out + (size_t)RAYS * 3 + (size_t)ray * NS + 8 * sl;
        *reinterpret_cast<float4*>(wrow)     = make_float4(wi[0], wi[1], wi[2], wi[3]);
        *reinterpret_cast<float4*>(wrow + 4) = make_float4(wi[4], wi[5], wi[6], wi[7]);
    }

    // ---- rgb from LDS c, per-half reduce (wi==0 kills clamped lanes) ----
    const float* crow = smf + ((T_F4 + S_F4) * 4) + rl * (NS * 3) + 24 * sls;
    float a0 = 0.f, a1 = 0.f, a2 = 0.f;
    #pragma unroll
    for (int m = 0; m < 6; ++m){
        float4 cc = *reinterpret_cast<const float4*>(crow + 4 * m);
        // elements 4m..4m+3 of the 24-float row
        int base = 4 * m;           // = 3*r + ch decomposed below
        float e0 = cc.x, e1 = cc.y, e2 = cc.z, e3 = cc.w;
        // accumulate into the right channel: index k = base+j, r = k/3, ch = k%3
        #pragma unroll
        for (int j = 0; j < 4; ++j){
            float e = (j == 0) ? e0 : (j == 1) ? e1 : (j == 2) ? e2 : e3;
            int k  = base + j;
            int rr = k / 3, ch = k % 3;     // compile-time constants after unroll
            if      (ch == 0) a0 += wi[rr] * e;
            else if (ch == 1) a1 += wi[rr] * e;
            else              a2 += wi[rr] * e;
        }
    }
    a0 = halfsum(a0);
    a1 = halfsum(a1);
    a2 = halfsum(a2);
    if (sl < 3){
        float val = (sl == 0) ? a0 : ((sl == 1) ? a1 : a2);
        out[(size_t)ray * 3 + sl] = val;
    }
}

extern "C" void kernel_launch(void* const* d_in, const int* in_sizes, int n_in,
                              void* d_out, int out_size, void* d_ws, size_t ws_size,
                              hipStream_t stream) {
    const float* t     = (const float*)d_in[0];
    const float* sigma = (const float*)d_in[1];
    const float* c     = (const float*)d_in[2];
    float* out = (float*)d_out;
    nerf_integrate<<<RAYS / 8, 256, 0, stream>>>(t, sigma, c, out);
}